// Round 3
// baseline (510.689 us; speedup 1.0000x reference)
//
#include <hip/hip_runtime.h>

#define NQ 1764
#define NQP 1792             // keys padded to 28*64, zero-filled by prep
#define DIM 256
#define KT 32                // keys per attn tile
#define NT_G 28              // tiles per key-group (2 groups x 28 = 56 total)
#define QBLK 112             // queries stored per block (16 blocks/batch)

// ---- attn LDS map (halfword units) ----
// RM buffers: [g][i] at (g*2+i)*RM_SZ          (4 x 8192 hw)
// TR buffers: [g][i] at 4*RM_SZ + (g*2+i)*TR_SZ (4 x 8192 hw)
// P region at P_OFF (8 waves x 32 rows x P_STRIDE)
#define RM_SZ (KT * DIM)                  // 8192 hw: [32 keys][256 d]
#define TR_SZ (DIM * KT)                  // 8192 hw: [256 d][32 keys]
#define P_OFF (4 * RM_SZ + 4 * TR_SZ)     // 65536
#define P_STRIDE 40
#define SM_TOTAL (P_OFF + 8 * 32 * P_STRIDE)   // 75776 hw = 151552 B

// ---- epilogue merge map (float units, reuses sm; all tile/P data dead) ----
#define PAIR_F 8320          // per wave-pair: [32 q][260] fp32 (260 = pad vs conflicts)
#define L_OFF_F (4 * PAIR_F) // group-1 row sums l

// ---- workspace map (ushort units) ----
#define WS_MRM_SZ (16 * NQP * DIM)
#define WS_MTR_SZ (16 * DIM * NQP)

typedef __attribute__((ext_vector_type(4))) short short4v;
typedef __attribute__((ext_vector_type(8))) short short8v;
typedef __attribute__((ext_vector_type(4))) float float4v;

static __device__ __forceinline__ ushort f2bf(float f) {
  union { float f; unsigned u; } v; v.f = f;
  return (ushort)((v.u + 0x7FFFu + ((v.u >> 16) & 1u)) >> 16);  // RNE
}

// async global->LDS DMA, 16 B per lane; LDS dest = wave-uniform base + lane*16
static __device__ __forceinline__ void dma16(const void* g, void* l) {
  __builtin_amdgcn_global_load_lds(
      (__attribute__((address_space(1))) void*)(void*)g,
      (__attribute__((address_space(3))) void*)l, 16, 0, 0);
}

// ============================ prep: m -> bf16 RM + TR ============================
// smf layout is chunk-XOR swizzled: logical (row, d) lives at float index
// row*260 + ((d>>2) ^ (row>>3))*4 + (d&3).  On the transpose read the 8
// kc-lanes (row>>3 = kc) then fan across 8 distinct bank offsets instead of
// all aliasing to one bank (kc*8*260 == 0 mod 32).
__global__ __launch_bounds__(256)
void prep_m(const float* __restrict__ mg, ushort* __restrict__ mrm,
            ushort* __restrict__ mtr)
{
  __shared__ float smf[64 * 260];
  const int tid = threadIdx.x;
  const int b   = blockIdx.x & 15;
  const int kt  = blockIdx.x >> 4;      // 0..27, 64-key chunks
  const int k0  = kt * 64;
  const float* mb = mg + (size_t)b * NQ * DIM;

  #pragma unroll
  for (int i = 0; i < 16; ++i) {
    const int idx = i * 256 + tid;
    const int row = idx >> 6;           // 0..63 (key within chunk)
    const int ch  = idx & 63;           // 4-float chunk of d
    const int c4  = ch * 4;
    const int gk  = k0 + row;
    float4v v = (gk < NQ) ? *(const float4v*)(mb + (size_t)gk * DIM + c4)
                          : (float4v){0.f, 0.f, 0.f, 0.f};
    *(float4v*)&smf[row * 260 + ((ch ^ (row >> 3)) << 2)] = v;
    union { short4v v4; short e[4]; } h;
    #pragma unroll
    for (int j = 0; j < 4; ++j) h.e[j] = (short)f2bf(v[j]);
    *(short4v*)(mrm + ((size_t)b * NQP + k0 + row) * DIM + c4) = h.v4;
  }
  __syncthreads();

  // transposed write, coalesced: per instruction 8 lanes cover 128 contiguous
  // bytes of one d-row; 8 d-rows per instruction.
  const int wv = tid >> 6;        // wave 0..3
  const int ln = tid & 63;
  const int dr = ln >> 3;         // 0..7: d-row within the 8-row strip
  const int kc = ln & 7;          // 0..7: 16B key-chunk within the 64-key block
  #pragma unroll
  for (int it = 0; it < 8; ++it) {
    const int d  = wv * 64 + it * 8 + dr;
    const int dc = d >> 2;        // logical 4-float chunk of d
    const int de = d & 3;
    union { short8v v; short e[8]; } u;
    #pragma unroll
    for (int j = 0; j < 8; ++j)
      u.e[j] = (short)f2bf(smf[(kc * 8 + j) * 260 + ((dc ^ kc) << 2) + de]);
    *(short8v*)(mtr + ((size_t)b * DIM + d) * NQP + k0 + kc * 8) = u.v;
  }
}

// ============================ attention ============================
// Block = 8 waves = 512 threads, 1 block/CU -> 2 waves/SIMD. Wave pair
// (wg, wg+4) owns the same 32 queries; group g = w>>2 streams key tiles
// g, g+2, ... (28 tiles each), double-buffered RM/TR via async DMA.
//
// Pipelined: iteration t runs PV[t-1] (P written last iter, LDS in-order per
// wave; pa reads precede this iter's P writes -> single-buffered P is WAR-
// safe), then QK[t]+exp+P-write. The exp -> P-LDS-roundtrip leaves the
// critical path. TR staging staggered one iter later than RM so double
// buffers still suffice. Masks prefetched one tile ahead.
//
// P region is chunk-XOR swizzled (chunk ^ quad on write, chunk ^ (l15>>2)
// on read): removes the 4-way bank conflict of quads {0,2}/{1,3} on the
// per-element P writes (stride 40 hw -> quad*16 bank offset collision).

static __device__ __forceinline__ void stage_RM(const ushort* mrb, ushort* smb,
                                                int k0, int wg, int lane)
{
  // RM [k][cs] <- global d-chunk cs^(k&7)  (swizzle in the global address)
  #pragma unroll
  for (int j = 0; j < 4; ++j) {
    const int L  = (wg * 4 + j) * 64 + lane;   // 0..1023
    const int k  = L >> 5;
    const int cs = L & 31;
    const int gc = cs ^ (k & 7);
    dma16(mrb + (size_t)(k0 + k) * DIM + gc * 8, smb + (wg * 4 + j) * 512);
  }
}

static __device__ __forceinline__ void stage_TR(const ushort* mtb, ushort* smb,
                                                int k0, int wg, int lane)
{
  // TR [d][t] <- global key-chunk (t ^ (d&3) ^ ((d>>2)&3)): the extra
  // (d>>2) term breaks the 4-way bank aliasing of lanes l15 = {0,4,8,12}
  // on the PV read side.
  #pragma unroll
  for (int j = 0; j < 4; ++j) {
    const int L = (wg * 4 + j) * 64 + lane;
    const int d = L >> 2;
    const int t = L & 3;
    const int kc = (t ^ (d & 3) ^ ((d >> 2) & 3)) & 3;
    dma16(mtb + (size_t)d * NQP + k0 + kc * 8, smb + (wg * 4 + j) * 512);
  }
}

__global__ __launch_bounds__(512, 2)
void attn_fused(const float* __restrict__ x, const ushort* __restrict__ mrm,
                const ushort* __restrict__ mtr, const int* __restrict__ maskg,
                const float* __restrict__ scale, float* __restrict__ out)
{
  __shared__ ushort sm[SM_TOTAL];
  const int tid  = threadIdx.x;
  const int w    = tid >> 6;      // 0..7
  const int lane = tid & 63;
  const int l15  = lane & 15;
  const int quad = lane >> 4;
  const int l7   = l15 & 7;
  const int g    = w >> 2;        // key group: 0 = even tiles, 1 = odd tiles
  const int wg   = w & 3;         // wave-within-group = query sub-block

  const int b      = blockIdx.x & 15;
  const int qblk   = blockIdx.x >> 4;     // 0..15
  const int qbase0 = qblk * QBLK;
  const int qbase  = qbase0 + wg * 32;

  const float*  xb  = x + (size_t)b * NQ * DIM;
  const ushort* mrb = mrm + (size_t)b * NQP * DIM;
  const ushort* mtb = mtr + (size_t)b * DIM * NQP;
  const int*    mkb = maskg + (size_t)b * NQ;
  float*        ob  = out + (size_t)b * NQ * (2 * DIM);

  // ---- resident Q fragments: two 16-q subtiles, Q = x*scale, bf16, A-layout ----
  short8v qa0[8], qa1[8];
  {
    int q0 = qbase + l15;      q0 = q0 < NQ ? q0 : NQ - 1;
    int q1 = qbase + 16 + l15; q1 = q1 < NQ ? q1 : NQ - 1;
    const float* xr0 = xb + (size_t)q0 * DIM;
    const float* xr1 = xb + (size_t)q1 * DIM;
    #pragma unroll
    for (int kk = 0; kk < 8; ++kk) {
      const int dof = kk * 32 + quad * 8;
      const float4v sa = *(const float4v*)(scale + dof);
      const float4v sb = *(const float4v*)(scale + dof + 4);
      const float4v a0 = *(const float4v*)(xr0 + dof);
      const float4v a1 = *(const float4v*)(xr0 + dof + 4);
      const float4v b0 = *(const float4v*)(xr1 + dof);
      const float4v b1 = *(const float4v*)(xr1 + dof + 4);
      union { short8v v; short e[8]; } u0, u1;
      #pragma unroll
      for (int j = 0; j < 4; ++j) {
        u0.e[j]     = (short)f2bf(a0[j] * sa[j]);
        u0.e[j + 4] = (short)f2bf(a1[j] * sb[j]);
        u1.e[j]     = (short)f2bf(b0[j] * sa[j]);
        u1.e[j + 4] = (short)f2bf(b1[j] * sb[j]);
      }
      qa0[kk] = u0.v;
      qa1[kk] = u1.v;
    }
  }

  float4v o0[16], o1[16];
  #pragma unroll
  for (int dt = 0; dt < 16; ++dt) {
    o0[dt] = (float4v){0.f, 0.f, 0.f, 0.f};
    o1[dt] = (float4v){0.f, 0.f, 0.f, 0.f};
  }
  float l0[4] = {0.f, 0.f, 0.f, 0.f};
  float l1[4] = {0.f, 0.f, 0.f, 0.f};

  // prologue: stage RM[tile g] -> rm buf 0; prefetch tile-0 mask
  stage_RM(mrb, sm + (g * 2 + 0) * RM_SZ, g * KT, wg, lane);
  int mvc[2];
  #pragma unroll
  for (int ks = 0; ks < 2; ++ks) {
    const int key = g * KT + ks * 16 + l15;
    mvc[ks] = (key < NQ) ? mkb[key] : 0;
  }

  #pragma unroll 1
  for (int t = 0; t <= NT_G; ++t) {
    __syncthreads();   // drains this wave's DMA (vmcnt 0) + syncs buffer reuse

    if (t < NT_G)
      stage_TR(mtb, sm + 4 * RM_SZ + (g * 2 + (t & 1)) * TR_SZ,
               (g + 2 * t) * KT, wg, lane);
    if (t + 1 < NT_G)
      stage_RM(mrb, sm + (g * 2 + ((t + 1) & 1)) * RM_SZ,
               (g + 2 * (t + 1)) * KT, wg, lane);

    // prefetch next tile's mask (consumed next iteration)
    int mvn[2] = {0, 0};
    if (t + 1 < NT_G) {
      #pragma unroll
      for (int ks = 0; ks < 2; ++ks) {
        const int key = (g + 2 * (t + 1)) * KT + ks * 16 + l15;
        mvn[ks] = (key < NQ) ? mkb[key] : 0;
      }
    }

    // ---- PV for tile t-1 (P written last iteration; pa reads precede this
    //      iteration's P writes in program order -> WAR-safe) ----
    if (t >= 1) {
      const ushort* trp = sm + 4 * RM_SZ + (g * 2 + ((t - 1) & 1)) * TR_SZ;
      const int pswz = (quad ^ (l15 >> 2)) << 3;   // chunk ^ (row>>2)&3, row=w*32(+16)+l15
      const short8v pa0 = *(const short8v*)&sm[P_OFF + (w * 32 + l15) * P_STRIDE + pswz];
      const short8v pa1 = *(const short8v*)&sm[P_OFF + (w * 32 + 16 + l15) * P_STRIDE + pswz];
      __builtin_amdgcn_s_setprio(1);
      #pragma unroll
      for (int dt = 0; dt < 16; ++dt) {
        const int d = dt * 16 + l15;
        const short8v bv = *(const short8v*)(
            trp + d * KT + (((quad ^ (d & 3) ^ ((d >> 2) & 3)) & 3) * 8));
        o0[dt] = __builtin_amdgcn_mfma_f32_16x16x32_bf16(pa0, bv, o0[dt], 0, 0, 0);
        o1[dt] = __builtin_amdgcn_mfma_f32_16x16x32_bf16(pa1, bv, o1[dt], 0, 0, 0);
      }
      __builtin_amdgcn_s_setprio(0);
    }

    // ---- QK for tile t: S = Q·m^T, p = mask?exp(s):0, write P ----
    if (t < NT_G) {
      const ushort* rmp = sm + (g * 2 + (t & 1)) * RM_SZ;
      #pragma unroll
      for (int ks = 0; ks < 2; ++ks) {
        float4v s0 = (float4v){0.f, 0.f, 0.f, 0.f};
        float4v s1 = (float4v){0.f, 0.f, 0.f, 0.f};
        const ushort* rowp = rmp + (ks * 16 + l15) * DIM;
        __builtin_amdgcn_s_setprio(1);
        #pragma unroll
        for (int kk = 0; kk < 8; ++kk) {
          const short8v bv = *(const short8v*)(rowp + (((kk * 4 + quad) ^ l7) * 8));
          s0 = __builtin_amdgcn_mfma_f32_16x16x32_bf16(qa0[kk], bv, s0, 0, 0, 0);
          s1 = __builtin_amdgcn_mfma_f32_16x16x32_bf16(qa1[kk], bv, s1, 0, 0, 0);
        }
        __builtin_amdgcn_s_setprio(0);
        // P write: logical col ks*16+l15 -> chunk (ks*2 + l15>>3) ^ quad
        const int pwc = (((ks * 2 + (l15 >> 3)) ^ quad) << 3) + l7;
        #pragma unroll
        for (int r = 0; r < 4; ++r) {
          const float p0 = mvc[ks] ? exp2f(s0[r] * 1.44269504089f) : 0.0f;
          const float p1 = mvc[ks] ? exp2f(s1[r] * 1.44269504089f) : 0.0f;
          l0[r] += p0;
          l1[r] += p1;
          sm[P_OFF + (w * 32 + quad * 4 + r) * P_STRIDE + pwc] = f2bf(p0);
          sm[P_OFF + (w * 32 + 16 + quad * 4 + r) * P_STRIDE + pwc] = f2bf(p1);
        }
      }
      mvc[0] = mvn[0];
      mvc[1] = mvn[1];
    }
  }

  // ---- reduce l over the 16 lanes of each quad (raw sums; inverse after merge) ----
  float la0[4], la1[4];
  #pragma unroll
  for (int r = 0; r < 4; ++r) {
    float a = l0[r], c = l1[r];
    a += __shfl_xor(a, 1); a += __shfl_xor(a, 2);
    a += __shfl_xor(a, 4); a += __shfl_xor(a, 8);
    c += __shfl_xor(c, 1); c += __shfl_xor(c, 2);
    c += __shfl_xor(c, 4); c += __shfl_xor(c, 8);
    la0[r] = a;
    la1[r] = c;
  }

  __syncthreads();   // tiles + P dead; reuse LDS for the group merge
  float* fsm = (float*)sm;

  // ---- group 1 publishes its partial O and l ----
  if (g == 1) {
    float* pr = fsm + wg * PAIR_F;
    #pragma unroll
    for (int dt = 0; dt < 16; ++dt)
      #pragma unroll
      for (int r = 0; r < 4; ++r) {
        pr[(quad * 4 + r) * 260 + dt * 16 + l15]      = o0[dt][r];
        pr[(16 + quad * 4 + r) * 260 + dt * 16 + l15] = o1[dt][r];
      }
    if (l15 == 0) {
      #pragma unroll
      for (int r = 0; r < 4; ++r) {
        fsm[L_OFF_F + wg * 32 + quad * 4 + r]      = la0[r];
        fsm[L_OFF_F + wg * 32 + 16 + quad * 4 + r] = la1[r];
      }
    }
  }
  __syncthreads();

  // ---- group 0 merges: O += O_b, l += l_b, then inverse ----
  float il0[4], il1[4];
  if (g == 0) {
    float* pr = fsm + wg * PAIR_F;
    #pragma unroll
    for (int dt = 0; dt < 16; ++dt)
      #pragma unroll
      for (int r = 0; r < 4; ++r) {
        o0[dt][r] += pr[(quad * 4 + r) * 260 + dt * 16 + l15];
        o1[dt][r] += pr[(16 + quad * 4 + r) * 260 + dt * 16 + l15];
      }
    #pragma unroll
    for (int r = 0; r < 4; ++r) {
      il0[r] = 1.0f / (la0[r] + fsm[L_OFF_F + wg * 32 + quad * 4 + r]);
      il1[r] = 1.0f / (la1[r] + fsm[L_OFF_F + wg * 32 + 16 + quad * 4 + r]);
    }
  }
  __syncthreads();   // merge region dead; waves 0-3 reuse it for O transpose

  if (g == 0) {
    // ---- O transpose through LDS + coalesced float4 stores ----
    float* ew = fsm + wg * 4160;   // per-wave [16 q][260] fp32
    #pragma unroll
    for (int qs = 0; qs < 2; ++qs) {
      #pragma unroll
      for (int dt = 0; dt < 16; ++dt)
        #pragma unroll
        for (int r = 0; r < 4; ++r)
          ew[(quad * 4 + r) * 260 + dt * 16 + l15] =
              qs ? (o1[dt][r] * il1[r]) : (o0[dt][r] * il0[r]);
      #pragma unroll
      for (int i = 0; i < 4; ++i)
        #pragma unroll
        for (int jj = 0; jj < 4; ++jj) {
          const int row = i * 4 + quad;
          const int lq  = wg * 32 + qs * 16 + row;
          const int q   = qbase0 + lq;
          if (lq < QBLK && q < NQ) {
            const float4v v = *(const float4v*)&ew[row * 260 + (jj * 16 + l15) * 4];
            *(float4v*)(ob + (size_t)q * (2 * DIM) + DIM + (jj * 16 + l15) * 4) = v;
          }
        }
    }
  } else {
    // ---- copy x into first half of concat (block's own 112 queries) ----
    const int tid2 = tid - 256;
    #pragma unroll
    for (int i = 0; i < 28; ++i) {
      const int idx = i * 256 + tid2;     // 0..7167
      const int row = idx >> 6;           // 0..111
      const int c4  = (idx & 63) * 4;
      const int q   = qbase0 + row;
      if (q < NQ) {
        const float4v v = *(const float4v*)(xb + (size_t)q * DIM + c4);
        *(float4v*)(ob + (size_t)q * (2 * DIM) + c4) = v;
      }
    }
  }
}

extern "C" void kernel_launch(void* const* d_in, const int* in_sizes, int n_in,
                              void* d_out, int out_size, void* d_ws, size_t ws_size,
                              hipStream_t stream) {
  const float* x     = (const float*)d_in[0];
  const float* mem   = (const float*)d_in[1];
  const int*   mask  = (const int*)d_in[2];
  // d_in[3] = w_lin: cancels in softmax (per-row constant) — unused
  const float* scale = (const float*)d_in[4];
  float* out = (float*)d_out;

  ushort* wsm = (ushort*)d_ws;               // bf16 m, row-major [16][1792][256]
  ushort* wst = wsm + WS_MRM_SZ;             // bf16 m, transposed [16][256][1792]

  prep_m<<<dim3(448), dim3(256), 0, stream>>>(mem, wsm, wst);
  // 16 batches x 16 q-blocks of 112 queries = 256 blocks = 1 per CU,
  // 8 waves/block (2 key-groups x 4 query-waves) = 2 waves/SIMD
  attn_fused<<<dim3(256), dim3(512), 0, stream>>>(x, wsm, wst, mask, scale, out);
}

// Round 4
// 265.744 us; speedup vs baseline: 1.9217x; 1.9217x over previous
//
#include <hip/hip_runtime.h>

#define NQ 1764
#define NQP 1792             // keys padded to 28*64, zero-filled by prep
#define DIM 256
#define KT 32                // keys per attn tile
#define NT_G 28              // tiles per key-group (2 groups x 28 = 56 total)
#define QBLK 112             // queries stored per block (16 blocks/batch)

// ---- attn LDS map (halfword units) ----
// two key-groups, each double-buffered: 4 x BUF_SZ, then 8-wave P region
#define RM_SZ (KT * DIM)                  // 8192 hw: [32 keys][256 d]
#define TR_SZ (DIM * KT)                  // 8192 hw: [256 d][32 keys]
#define BUF_SZ (RM_SZ + TR_SZ)            // 16384
#define P_OFF (4 * BUF_SZ)                // 65536
#define P_STRIDE 40
#define SM_TOTAL (P_OFF + 8 * 32 * P_STRIDE)   // 75776 hw = 151552 B

// ---- epilogue merge map (float units, reuses sm; all tile/P data dead) ----
#define PAIR_F 8320          // per wave-pair: [32 q][260] fp32 (260 = pad vs conflicts)
#define L_OFF_F (4 * PAIR_F) // group-1 row sums l

// ---- workspace map (ushort units) ----
#define WS_MRM_SZ (16 * NQP * DIM)
#define WS_MTR_SZ (16 * DIM * NQP)

typedef __attribute__((ext_vector_type(4))) short short4v;
typedef __attribute__((ext_vector_type(8))) short short8v;
typedef __attribute__((ext_vector_type(4))) float float4v;

static __device__ __forceinline__ ushort f2bf(float f) {
  union { float f; unsigned u; } v; v.f = f;
  return (ushort)((v.u + 0x7FFFu + ((v.u >> 16) & 1u)) >> 16);  // RNE
}

// async global->LDS DMA, 16 B per lane; LDS dest = wave-uniform base + lane*16
static __device__ __forceinline__ void dma16(const void* g, void* l) {
  __builtin_amdgcn_global_load_lds(
      (__attribute__((address_space(1))) void*)(void*)g,
      (__attribute__((address_space(3))) void*)l, 16, 0, 0);
}

// ============================ prep: m -> bf16 RM + TR ============================
// smf layout is chunk-XOR swizzled: logical (row, d) lives at float index
// row*260 + ((d>>2) ^ (row>>3))*4 + (d&3).  On the transpose read the 8
// kc-lanes (row>>3 = kc) then fan across distinct banks (2-way = free)
// instead of 8-way aliasing (kc*8*260 == 0 mod 32).
__global__ __launch_bounds__(256)
void prep_m(const float* __restrict__ mg, ushort* __restrict__ mrm,
            ushort* __restrict__ mtr)
{
  __shared__ float smf[64 * 260];
  const int tid = threadIdx.x;
  const int b   = blockIdx.x & 15;
  const int kt  = blockIdx.x >> 4;      // 0..27, 64-key chunks
  const int k0  = kt * 64;
  const float* mb = mg + (size_t)b * NQ * DIM;

  #pragma unroll
  for (int i = 0; i < 16; ++i) {
    const int idx = i * 256 + tid;
    const int row = idx >> 6;           // 0..63 (key within chunk)
    const int ch  = idx & 63;           // 4-float chunk of d
    const int c4  = ch * 4;
    const int gk  = k0 + row;
    float4v v = (gk < NQ) ? *(const float4v*)(mb + (size_t)gk * DIM + c4)
                          : (float4v){0.f, 0.f, 0.f, 0.f};
    *(float4v*)&smf[row * 260 + ((ch ^ (row >> 3)) << 2)] = v;
    union { short4v v4; short e[4]; } h;
    #pragma unroll
    for (int j = 0; j < 4; ++j) h.e[j] = (short)f2bf(v[j]);
    *(short4v*)(mrm + ((size_t)b * NQP + k0 + row) * DIM + c4) = h.v4;
  }
  __syncthreads();

  // transposed write, coalesced: per instruction 8 lanes cover 128 contiguous
  // bytes of one d-row; 8 d-rows per instruction.
  const int wv = tid >> 6;        // wave 0..3
  const int ln = tid & 63;
  const int dr = ln >> 3;         // 0..7: d-row within the 8-row strip
  const int kc = ln & 7;          // 0..7: 16B key-chunk within the 64-key block
  #pragma unroll
  for (int it = 0; it < 8; ++it) {
    const int d  = wv * 64 + it * 8 + dr;
    const int dc = d >> 2;        // logical 4-float chunk of d
    const int de = d & 3;
    union { short8v v; short e[8]; } u;
    #pragma unroll
    for (int j = 0; j < 8; ++j)
      u.e[j] = (short)f2bf(smf[(kc * 8 + j) * 260 + ((dc ^ kc) << 2) + de]);
    *(short8v*)(mtr + ((size_t)b * DIM + d) * NQP + k0 + kc * 8) = u.v;
  }
}

// ============================ attention ============================
// Block = 8 waves = 512 threads, 1 block/CU -> 2 waves/SIMD. Wave pair
// (wg, wg+4) owns the same 32 queries; group g = w>>2 streams key tiles
// g, g+2, ... (28 tiles each) with its own double-buffered LDS pair.
// ROUND-1 SCHEDULE (known-good: L2 keeps each XCD's 2-batch m resident,
// FETCH ~52MB): stage tile t+1, QK[t], P roundtrip, PV[t], one barrier/iter.
// Round-3's PV-lag pipelining destroyed the cross-block L2 reuse
// (FETCH 52->718MB) — do not reintroduce without solving that.
//
// P region is chunk-XOR swizzled (chunk ^ quad on write, chunk ^ (l15>>2)
// on read — involution, since writer row>>2 & 3 == quad): P writes go from
// 4-way bank conflict to free 2-way. TR carries an extra ^((d>>2)&3) so PV's
// ds_read_b128 lanes spread 8-per-4-bank-group instead of 16.

static __device__ __forceinline__ void stage_tile(const ushort* mrb, const ushort* mtb,
                                                  ushort* smb, int k0, int wg, int lane)
{
  // RM [k][cs] <- global d-chunk cs^(k&7)  (swizzle in the global address)
  #pragma unroll
  for (int j = 0; j < 4; ++j) {
    const int L  = (wg * 4 + j) * 64 + lane;   // 0..1023
    const int k  = L >> 5;
    const int cs = L & 31;
    const int gc = cs ^ (k & 7);
    dma16(mrb + (size_t)(k0 + k) * DIM + gc * 8, smb + (wg * 4 + j) * 512);
  }
  // TR [d][t] <- global key-chunk t ^ (d&3) ^ ((d>>2)&3)
  #pragma unroll
  for (int j = 0; j < 4; ++j) {
    const int L = (wg * 4 + j) * 64 + lane;
    const int d = L >> 2;
    const int t = L & 3;
    const int kc = (t ^ (d & 3) ^ ((d >> 2) & 3)) & 3;
    dma16(mtb + (size_t)d * NQP + k0 + kc * 8, smb + RM_SZ + (wg * 4 + j) * 512);
  }
}

__global__ __launch_bounds__(512, 2)
void attn_fused(const float* __restrict__ x, const ushort* __restrict__ mrm,
                const ushort* __restrict__ mtr, const int* __restrict__ maskg,
                const float* __restrict__ scale, float* __restrict__ out)
{
  __shared__ ushort sm[SM_TOTAL];
  const int tid  = threadIdx.x;
  const int w    = tid >> 6;      // 0..7
  const int lane = tid & 63;
  const int l15  = lane & 15;
  const int quad = lane >> 4;
  const int l7   = l15 & 7;
  const int g    = w >> 2;        // key group: 0 = even tiles, 1 = odd tiles
  const int wg   = w & 3;         // wave-within-group = query sub-block

  const int b      = blockIdx.x & 15;
  const int qblk   = blockIdx.x >> 4;     // 0..15
  const int qbase0 = qblk * QBLK;
  const int qbase  = qbase0 + wg * 32;

  const float*  xb  = x + (size_t)b * NQ * DIM;
  const ushort* mrb = mrm + (size_t)b * NQP * DIM;
  const ushort* mtb = mtr + (size_t)b * DIM * NQP;
  const int*    mkb = maskg + (size_t)b * NQ;
  float*        ob  = out + (size_t)b * NQ * (2 * DIM);

  // ---- resident Q fragments: two 16-q subtiles, Q = x*scale, bf16, A-layout ----
  short8v qa0[8], qa1[8];
  {
    int q0 = qbase + l15;      q0 = q0 < NQ ? q0 : NQ - 1;
    int q1 = qbase + 16 + l15; q1 = q1 < NQ ? q1 : NQ - 1;
    const float* xr0 = xb + (size_t)q0 * DIM;
    const float* xr1 = xb + (size_t)q1 * DIM;
    #pragma unroll
    for (int kk = 0; kk < 8; ++kk) {
      const int dof = kk * 32 + quad * 8;
      const float4v sa = *(const float4v*)(scale + dof);
      const float4v sb = *(const float4v*)(scale + dof + 4);
      const float4v a0 = *(const float4v*)(xr0 + dof);
      const float4v a1 = *(const float4v*)(xr0 + dof + 4);
      const float4v b0 = *(const float4v*)(xr1 + dof);
      const float4v b1 = *(const float4v*)(xr1 + dof + 4);
      union { short8v v; short e[8]; } u0, u1;
      #pragma unroll
      for (int j = 0; j < 4; ++j) {
        u0.e[j]     = (short)f2bf(a0[j] * sa[j]);
        u0.e[j + 4] = (short)f2bf(a1[j] * sb[j]);
        u1.e[j]     = (short)f2bf(b0[j] * sa[j]);
        u1.e[j + 4] = (short)f2bf(b1[j] * sb[j]);
      }
      qa0[kk] = u0.v;
      qa1[kk] = u1.v;
    }
  }

  float4v o0[16], o1[16];
  #pragma unroll
  for (int dt = 0; dt < 16; ++dt) {
    o0[dt] = (float4v){0.f, 0.f, 0.f, 0.f};
    o1[dt] = (float4v){0.f, 0.f, 0.f, 0.f};
  }
  float l0[4] = {0.f, 0.f, 0.f, 0.f};
  float l1[4] = {0.f, 0.f, 0.f, 0.f};

  // prefetch this group's tile 0 (tile index g) -> group buf 0; tile-0 mask
  stage_tile(mrb, mtb, sm + g * 2 * BUF_SZ, g * KT, wg, lane);
  int mvc[2];
  #pragma unroll
  for (int ks = 0; ks < 2; ++ks) {
    const int key = g * KT + ks * 16 + l15;
    mvc[ks] = (key < NQ) ? mkb[key] : 0;
  }

  #pragma unroll 1
  for (int t = 0; t < NT_G; ++t) {
    __syncthreads();   // drains this wave's DMA (vmcnt 0) + syncs buffer reuse
    if (t + 1 < NT_G)
      stage_tile(mrb, mtb, sm + (g * 2 + ((t + 1) & 1)) * BUF_SZ,
                 (g + 2 * (t + 1)) * KT, wg, lane);

    // prefetch next tile's mask (consumed next iteration)
    int mvn[2] = {0, 0};
    if (t + 1 < NT_G) {
      #pragma unroll
      for (int ks = 0; ks < 2; ++ks) {
        const int key = (g + 2 * (t + 1)) * KT + ks * 16 + l15;
        mvn[ks] = (key < NQ) ? mkb[key] : 0;
      }
    }

    const ushort* rmp = sm + (g * 2 + (t & 1)) * BUF_SZ;
    const ushort* trp = rmp + RM_SZ;

    // ---- S = Q·m^T (B-frag shared by both q-subtiles), p = mask?exp(s):0 ----
    #pragma unroll
    for (int ks = 0; ks < 2; ++ks) {
      float4v s0 = (float4v){0.f, 0.f, 0.f, 0.f};
      float4v s1 = (float4v){0.f, 0.f, 0.f, 0.f};
      const ushort* rowp = rmp + (ks * 16 + l15) * DIM;
      #pragma unroll
      for (int kk = 0; kk < 8; ++kk) {
        const short8v bv = *(const short8v*)(rowp + (((kk * 4 + quad) ^ l7) * 8));
        s0 = __builtin_amdgcn_mfma_f32_16x16x32_bf16(qa0[kk], bv, s0, 0, 0, 0);
        s1 = __builtin_amdgcn_mfma_f32_16x16x32_bf16(qa1[kk], bv, s1, 0, 0, 0);
      }
      // P write: logical chunk (ks*2 + l15>>3) stored at chunk ^ quad
      const int pwc = (((ks * 2 + (l15 >> 3)) ^ quad) << 3) + l7;
      #pragma unroll
      for (int r = 0; r < 4; ++r) {
        const float p0 = mvc[ks] ? exp2f(s0[r] * 1.44269504089f) : 0.0f;
        const float p1 = mvc[ks] ? exp2f(s1[r] * 1.44269504089f) : 0.0f;
        l0[r] += p0;
        l1[r] += p1;
        sm[P_OFF + (w * 32 + quad * 4 + r) * P_STRIDE + pwc] = f2bf(p0);
        sm[P_OFF + (w * 32 + 16 + quad * 4 + r) * P_STRIDE + pwc] = f2bf(p1);
      }
    }
    mvc[0] = mvn[0];
    mvc[1] = mvn[1];

    // ---- O += P·m (B-frag shared by both q-subtiles) ----
    {
      // reader row>>2 & 3 == l15>>2, writer's == quad: physical = logical^swz
      const int pswz = ((quad ^ (l15 >> 2)) & 3) << 3;
      const short8v pa0 = *(const short8v*)&sm[P_OFF + (w * 32 + l15) * P_STRIDE + pswz];
      const short8v pa1 = *(const short8v*)&sm[P_OFF + (w * 32 + 16 + l15) * P_STRIDE + pswz];
      #pragma unroll
      for (int dt = 0; dt < 16; ++dt) {
        const int d = dt * 16 + l15;
        const short8v bv = *(const short8v*)(
            trp + d * KT + (((quad ^ (d & 3) ^ ((d >> 2) & 3)) & 3) * 8));
        o0[dt] = __builtin_amdgcn_mfma_f32_16x16x32_bf16(pa0, bv, o0[dt], 0, 0, 0);
        o1[dt] = __builtin_amdgcn_mfma_f32_16x16x32_bf16(pa1, bv, o1[dt], 0, 0, 0);
      }
    }
  }

  // ---- reduce l over the 16 lanes of each quad (raw sums; inverse after merge) ----
  float la0[4], la1[4];
  #pragma unroll
  for (int r = 0; r < 4; ++r) {
    float a = l0[r], c = l1[r];
    a += __shfl_xor(a, 1); a += __shfl_xor(a, 2);
    a += __shfl_xor(a, 4); a += __shfl_xor(a, 8);
    c += __shfl_xor(c, 1); c += __shfl_xor(c, 2);
    c += __shfl_xor(c, 4); c += __shfl_xor(c, 8);
    la0[r] = a;
    la1[r] = c;
  }

  __syncthreads();   // tiles + P dead; reuse LDS for the group merge
  float* fsm = (float*)sm;

  // ---- group 1 publishes its partial O and l ----
  if (g == 1) {
    float* pr = fsm + wg * PAIR_F;
    #pragma unroll
    for (int dt = 0; dt < 16; ++dt)
      #pragma unroll
      for (int r = 0; r < 4; ++r) {
        pr[(quad * 4 + r) * 260 + dt * 16 + l15]      = o0[dt][r];
        pr[(16 + quad * 4 + r) * 260 + dt * 16 + l15] = o1[dt][r];
      }
    if (l15 == 0) {
      #pragma unroll
      for (int r = 0; r < 4; ++r) {
        fsm[L_OFF_F + wg * 32 + quad * 4 + r]      = la0[r];
        fsm[L_OFF_F + wg * 32 + 16 + quad * 4 + r] = la1[r];
      }
    }
  }
  __syncthreads();

  // ---- group 0 merges: O += O_b, l += l_b, then inverse ----
  float il0[4], il1[4];
  if (g == 0) {
    float* pr = fsm + wg * PAIR_F;
    #pragma unroll
    for (int dt = 0; dt < 16; ++dt)
      #pragma unroll
      for (int r = 0; r < 4; ++r) {
        o0[dt][r] += pr[(quad * 4 + r) * 260 + dt * 16 + l15];
        o1[dt][r] += pr[(16 + quad * 4 + r) * 260 + dt * 16 + l15];
      }
    #pragma unroll
    for (int r = 0; r < 4; ++r) {
      il0[r] = 1.0f / (la0[r] + fsm[L_OFF_F + wg * 32 + quad * 4 + r]);
      il1[r] = 1.0f / (la1[r] + fsm[L_OFF_F + wg * 32 + 16 + quad * 4 + r]);
    }
  }
  __syncthreads();   // merge region dead; waves 0-3 reuse it for O transpose

  if (g == 0) {
    // ---- O transpose through LDS + coalesced float4 stores ----
    float* ew = fsm + wg * 4160;   // per-wave [16 q][260] fp32
    #pragma unroll
    for (int qs = 0; qs < 2; ++qs) {
      #pragma unroll
      for (int dt = 0; dt < 16; ++dt)
        #pragma unroll
        for (int r = 0; r < 4; ++r)
          ew[(quad * 4 + r) * 260 + dt * 16 + l15] =
              qs ? (o1[dt][r] * il1[r]) : (o0[dt][r] * il0[r]);
      #pragma unroll
      for (int i = 0; i < 4; ++i)
        #pragma unroll
        for (int jj = 0; jj < 4; ++jj) {
          const int row = i * 4 + quad;
          const int lq  = wg * 32 + qs * 16 + row;
          const int q   = qbase0 + lq;
          if (lq < QBLK && q < NQ) {
            const float4v v = *(const float4v*)&ew[row * 260 + (jj * 16 + l15) * 4];
            *(float4v*)(ob + (size_t)q * (2 * DIM) + DIM + (jj * 16 + l15) * 4) = v;
          }
        }
    }
  } else {
    // ---- copy x into first half of concat (block's own 112 queries) ----
    const int tid2 = tid - 256;
    #pragma unroll
    for (int i = 0; i < 28; ++i) {
      const int idx = i * 256 + tid2;     // 0..7167
      const int row = idx >> 6;           // 0..111
      const int c4  = (idx & 63) * 4;
      const int q   = qbase0 + row;
      if (q < NQ) {
        const float4v v = *(const float4v*)(xb + (size_t)q * DIM + c4);
        *(float4v*)(ob + (size_t)q * (2 * DIM) + c4) = v;
      }
    }
  }
}

extern "C" void kernel_launch(void* const* d_in, const int* in_sizes, int n_in,
                              void* d_out, int out_size, void* d_ws, size_t ws_size,
                              hipStream_t stream) {
  const float* x     = (const float*)d_in[0];
  const float* mem   = (const float*)d_in[1];
  const int*   mask  = (const int*)d_in[2];
  // d_in[3] = w_lin: cancels in softmax (per-row constant) — unused
  const float* scale = (const float*)d_in[4];
  float* out = (float*)d_out;

  ushort* wsm = (ushort*)d_ws;               // bf16 m, row-major [16][1792][256]
  ushort* wst = wsm + WS_MRM_SZ;             // bf16 m, transposed [16][256][1792]

  prep_m<<<dim3(448), dim3(256), 0, stream>>>(mem, wsm, wst);
  // 16 batches x 16 q-blocks of 112 queries = 256 blocks = 1 per CU,
  // 8 waves/block (2 key-groups x 4 query-waves) = 2 waves/SIMD
  attn_fused<<<dim3(256), dim3(512), 0, stream>>>(x, wsm, wst, mask, scale, out);
}

// Round 5
// 211.739 us; speedup vs baseline: 2.4119x; 1.2551x over previous
//
#include <hip/hip_runtime.h>

#define NQ 1764
#define NQP 1792             // keys padded to 28*64, zero-filled by prep
#define DIM 256
#define KT 32                // keys per attn tile
#define NT 56                // all key tiles, every block streams them
#define QBLK 64              // queries per block (28 blocks/batch)

// ---- attn LDS map (halfword units) ----
// double-buffered RM+TR tile, then 4-wave P region
#define RM_SZ (KT * DIM)                  // 8192 hw: [32 keys][256 d]
#define TR_SZ (DIM * KT)                  // 8192 hw: [256 d][32 keys]
#define BUF_SZ (RM_SZ + TR_SZ)            // 16384
#define P_OFF (2 * BUF_SZ)                // 32768
#define P_STRIDE 40
#define SM_TOTAL (P_OFF + 4 * 16 * P_STRIDE)   // 35328 hw = 70656 B -> 2 blocks/CU

// ---- workspace map (ushort units) ----
#define WS_MRM_SZ (16 * NQP * DIM)
#define WS_MTR_SZ (16 * DIM * NQP)

typedef __attribute__((ext_vector_type(4))) short short4v;
typedef __attribute__((ext_vector_type(8))) short short8v;
typedef __attribute__((ext_vector_type(4))) float float4v;

static __device__ __forceinline__ ushort f2bf(float f) {
  union { float f; unsigned u; } v; v.f = f;
  return (ushort)((v.u + 0x7FFFu + ((v.u >> 16) & 1u)) >> 16);  // RNE
}

// async global->LDS DMA, 16 B per lane; LDS dest = wave-uniform base + lane*16
static __device__ __forceinline__ void dma16(const void* g, void* l) {
  __builtin_amdgcn_global_load_lds(
      (__attribute__((address_space(1))) void*)(void*)g,
      (__attribute__((address_space(3))) void*)l, 16, 0, 0);
}

// ============================ prep: m -> bf16 RM + TR ============================
// (round-4 version, verified) smf chunk-XOR swizzled: logical (row,d) at float
// index row*260 + ((d>>2)^(row>>3))*4 + (d&3); transpose gather conflict-free,
// mtr writes 128B-contiguous per 8 lanes.
__global__ __launch_bounds__(256)
void prep_m(const float* __restrict__ mg, ushort* __restrict__ mrm,
            ushort* __restrict__ mtr)
{
  __shared__ float smf[64 * 260];
  const int tid = threadIdx.x;
  const int b   = blockIdx.x & 15;
  const int kt  = blockIdx.x >> 4;      // 0..27, 64-key chunks
  const int k0  = kt * 64;
  const float* mb = mg + (size_t)b * NQ * DIM;

  #pragma unroll
  for (int i = 0; i < 16; ++i) {
    const int idx = i * 256 + tid;
    const int row = idx >> 6;           // 0..63 (key within chunk)
    const int ch  = idx & 63;           // 4-float chunk of d
    const int c4  = ch * 4;
    const int gk  = k0 + row;
    float4v v = (gk < NQ) ? *(const float4v*)(mb + (size_t)gk * DIM + c4)
                          : (float4v){0.f, 0.f, 0.f, 0.f};
    *(float4v*)&smf[row * 260 + ((ch ^ (row >> 3)) << 2)] = v;
    union { short4v v4; short e[4]; } h;
    #pragma unroll
    for (int j = 0; j < 4; ++j) h.e[j] = (short)f2bf(v[j]);
    *(short4v*)(mrm + ((size_t)b * NQP + k0 + row) * DIM + c4) = h.v4;
  }
  __syncthreads();

  const int wv = tid >> 6;        // wave 0..3
  const int ln = tid & 63;
  const int dr = ln >> 3;         // 0..7: d-row within the 8-row strip
  const int kc = ln & 7;          // 0..7: 16B key-chunk within the 64-key block
  #pragma unroll
  for (int it = 0; it < 8; ++it) {
    const int d  = wv * 64 + it * 8 + dr;
    const int dc = d >> 2;        // logical 4-float chunk of d
    const int de = d & 3;
    union { short8v v; short e[8]; } u;
    #pragma unroll
    for (int j = 0; j < 8; ++j)
      u.e[j] = (short)f2bf(smf[(kc * 8 + j) * 260 + ((dc ^ kc) << 2) + de]);
    *(short8v*)(mtr + ((size_t)b * DIM + d) * NQP + k0 + kc * 8) = u.v;
  }
}

// ============================ attention ============================
// CONVOY-BREAK RESTRUCTURE: 448 blocks x 256 threads (4 waves), 2 blocks/CU.
// Each block owns 64 queries (wave w: 16 q, ONE MFMA subtile) and streams ALL
// 56 key-tiles (round-1-proven schedule: stage t+1, QK[t], P roundtrip, PV[t],
// one barrier per iter). The two co-resident blocks are independent barrier
// domains -> their phases interleave (stage/QK/exp/PV overlap across blocks),
// which the old 8-wave single-barrier block could not do (pipes used
// sequentially: MFMA 2.0K + VALU 2.8K + LDS 3.8K + DMA 1.2K ~= the 14K-cycle
// iteration).
// b = blockIdx&15 preserved -> each XCD still serves exactly 2 batches, m
// stays L2-resident (round-3 lesson: FETCH must stay ~53MB).

static __device__ __forceinline__ void stage_tile(const ushort* mrb, const ushort* mtb,
                                                  ushort* smb, int k0, int w, int lane)
{
  // RM [k][cs] <- global d-chunk cs^(k&7)  (swizzle in the global address)
  #pragma unroll
  for (int j = 0; j < 4; ++j) {
    const int L  = (w * 4 + j) * 64 + lane;   // 0..1023
    const int k  = L >> 5;
    const int cs = L & 31;
    const int gc = cs ^ (k & 7);
    dma16(mrb + (size_t)(k0 + k) * DIM + gc * 8, smb + (w * 4 + j) * 512);
  }
  // TR [d][t] <- global key-chunk t ^ (d&3) ^ ((d>>2)&3)
  #pragma unroll
  for (int j = 0; j < 4; ++j) {
    const int L = (w * 4 + j) * 64 + lane;
    const int d = L >> 2;
    const int t = L & 3;
    const int kc = (t ^ (d & 3) ^ ((d >> 2) & 3)) & 3;
    dma16(mtb + (size_t)d * NQP + k0 + kc * 8, smb + RM_SZ + (w * 4 + j) * 512);
  }
}

__global__ __launch_bounds__(256, 2)
void attn_fused(const float* __restrict__ x, const ushort* __restrict__ mrm,
                const ushort* __restrict__ mtr, const int* __restrict__ maskg,
                const float* __restrict__ scale, float* __restrict__ out)
{
  __shared__ ushort sm[SM_TOTAL];
  const int tid  = threadIdx.x;
  const int w    = tid >> 6;      // 0..3
  const int lane = tid & 63;
  const int l15  = lane & 15;
  const int quad = lane >> 4;
  const int l7   = l15 & 7;

  const int b      = blockIdx.x & 15;
  const int qblk   = blockIdx.x >> 4;     // 0..27
  const int qbase0 = qblk * QBLK;
  const int qbase  = qbase0 + w * 16;

  const float*  xb  = x + (size_t)b * NQ * DIM;
  const ushort* mrb = mrm + (size_t)b * NQP * DIM;
  const ushort* mtb = mtr + (size_t)b * DIM * NQP;
  const int*    mkb = maskg + (size_t)b * NQ;
  float*        ob  = out + (size_t)b * NQ * (2 * DIM);

  // ---- resident Q fragment: one 16-q subtile, Q = x*scale, bf16, A-layout ----
  short8v qa[8];
  {
    int q0 = qbase + l15; q0 = q0 < NQ ? q0 : NQ - 1;
    const float* xr0 = xb + (size_t)q0 * DIM;
    #pragma unroll
    for (int kk = 0; kk < 8; ++kk) {
      const int dof = kk * 32 + quad * 8;
      const float4v sa = *(const float4v*)(scale + dof);
      const float4v sb = *(const float4v*)(scale + dof + 4);
      const float4v a0 = *(const float4v*)(xr0 + dof);
      const float4v a1 = *(const float4v*)(xr0 + dof + 4);
      union { short8v v; short e[8]; } u0;
      #pragma unroll
      for (int j = 0; j < 4; ++j) {
        u0.e[j]     = (short)f2bf(a0[j] * sa[j]);
        u0.e[j + 4] = (short)f2bf(a1[j] * sb[j]);
      }
      qa[kk] = u0.v;
    }
  }

  float4v o[16];
  #pragma unroll
  for (int dt = 0; dt < 16; ++dt) o[dt] = (float4v){0.f, 0.f, 0.f, 0.f};
  float l0[4] = {0.f, 0.f, 0.f, 0.f};

  // prologue: stage tile 0 -> buf 0; prefetch tile-0 mask
  stage_tile(mrb, mtb, sm, 0, w, lane);
  int mvc[2];
  #pragma unroll
  for (int ks = 0; ks < 2; ++ks) {
    const int key = ks * 16 + l15;
    mvc[ks] = (key < NQ) ? mkb[key] : 0;
  }

  #pragma unroll 1
  for (int t = 0; t < NT; ++t) {
    __syncthreads();   // drains this wave's DMA (vmcnt 0) + syncs buffer reuse
    if (t + 1 < NT)
      stage_tile(mrb, mtb, sm + ((t + 1) & 1) * BUF_SZ, (t + 1) * KT, w, lane);

    // prefetch next tile's mask
    int mvn[2] = {0, 0};
    if (t + 1 < NT) {
      #pragma unroll
      for (int ks = 0; ks < 2; ++ks) {
        const int key = (t + 1) * KT + ks * 16 + l15;
        mvn[ks] = (key < NQ) ? mkb[key] : 0;
      }
    }

    const ushort* rmp = sm + (t & 1) * BUF_SZ;
    const ushort* trp = rmp + RM_SZ;

    // ---- S = Q·m^T, split into two 4-deep accumulator chains ----
    #pragma unroll
    for (int ks = 0; ks < 2; ++ks) {
      float4v sA = (float4v){0.f, 0.f, 0.f, 0.f};
      float4v sB = (float4v){0.f, 0.f, 0.f, 0.f};
      const ushort* rowp = rmp + (ks * 16 + l15) * DIM;
      #pragma unroll
      for (int kk = 0; kk < 4; ++kk) {
        const short8v bvA = *(const short8v*)(rowp + (((kk * 4 + quad) ^ l7) * 8));
        const short8v bvB = *(const short8v*)(rowp + ((((kk + 4) * 4 + quad) ^ l7) * 8));
        sA = __builtin_amdgcn_mfma_f32_16x16x32_bf16(qa[kk], bvA, sA, 0, 0, 0);
        sB = __builtin_amdgcn_mfma_f32_16x16x32_bf16(qa[kk + 4], bvB, sB, 0, 0, 0);
      }
      // P write: logical chunk (ks*2 + l15>>3) stored at chunk ^ quad
      const int pwc = (((ks * 2 + (l15 >> 3)) ^ quad) << 3) + l7;
      #pragma unroll
      for (int r = 0; r < 4; ++r) {
        const float s = sA[r] + sB[r];
        const float p = mvc[ks] ? exp2f(s * 1.44269504089f) : 0.0f;
        l0[r] += p;
        sm[P_OFF + (w * 16 + quad * 4 + r) * P_STRIDE + pwc] = f2bf(p);
      }
    }
    mvc[0] = mvn[0];
    mvc[1] = mvn[1];

    // ---- O += P·m ----
    {
      // reader row>>2 & 3 == l15>>2, writer's == quad: physical = logical^swz
      const int pswz = ((quad ^ (l15 >> 2)) & 3) << 3;
      const short8v pa = *(const short8v*)&sm[P_OFF + (w * 16 + l15) * P_STRIDE + pswz];
      #pragma unroll
      for (int dt = 0; dt < 16; ++dt) {
        const int d = dt * 16 + l15;
        const short8v bv = *(const short8v*)(
            trp + d * KT + (((quad ^ (d & 3) ^ ((d >> 2) & 3)) & 3) * 8));
        o[dt] = __builtin_amdgcn_mfma_f32_16x16x32_bf16(pa, bv, o[dt], 0, 0, 0);
      }
    }
  }

  // ---- reduce l over the 16 lanes of each quad ----
  float il[4];
  #pragma unroll
  for (int r = 0; r < 4; ++r) {
    float a = l0[r];
    a += __shfl_xor(a, 1); a += __shfl_xor(a, 2);
    a += __shfl_xor(a, 4); a += __shfl_xor(a, 8);
    il[r] = 1.0f / a;
  }

  __syncthreads();   // tiles + P dead; reuse LDS for O transpose
  float* fsm = (float*)sm;
  float* ew = fsm + w * 4160;   // per-wave [16 q][260] fp32
  #pragma unroll
  for (int dt = 0; dt < 16; ++dt)
    #pragma unroll
    for (int r = 0; r < 4; ++r)
      ew[(quad * 4 + r) * 260 + dt * 16 + l15] = o[dt][r] * il[r];
  #pragma unroll
  for (int i = 0; i < 4; ++i)
    #pragma unroll
    for (int jj = 0; jj < 4; ++jj) {
      const int row = i * 4 + quad;
      const int q   = qbase0 + w * 16 + row;
      if (q < NQ) {
        const float4v v = *(const float4v*)&ew[row * 260 + (jj * 16 + l15) * 4];
        *(float4v*)(ob + (size_t)q * (2 * DIM) + DIM + (jj * 16 + l15) * 4) = v;
      }
    }

  // ---- copy x into first half of concat (block's own 64 queries) ----
  #pragma unroll
  for (int i = 0; i < 16; ++i) {
    const int idx = i * 256 + tid;      // 0..4095
    const int row = idx >> 6;           // 0..63
    const int c4  = (idx & 63) * 4;
    const int q   = qbase0 + row;
    if (q < NQ) {
      const float4v v = *(const float4v*)(xb + (size_t)q * DIM + c4);
      *(float4v*)(ob + (size_t)q * (2 * DIM) + c4) = v;
    }
  }
}

extern "C" void kernel_launch(void* const* d_in, const int* in_sizes, int n_in,
                              void* d_out, int out_size, void* d_ws, size_t ws_size,
                              hipStream_t stream) {
  const float* x     = (const float*)d_in[0];
  const float* mem   = (const float*)d_in[1];
  const int*   mask  = (const int*)d_in[2];
  // d_in[3] = w_lin: cancels in softmax (per-row constant) — unused
  const float* scale = (const float*)d_in[4];
  float* out = (float*)d_out;

  ushort* wsm = (ushort*)d_ws;               // bf16 m, row-major [16][1792][256]
  ushort* wst = wsm + WS_MRM_SZ;             // bf16 m, transposed [16][256][1792]

  prep_m<<<dim3(448), dim3(256), 0, stream>>>(mem, wsm, wst);
  // 16 batches x 28 q-blocks of 64 queries = 448 blocks, 2 blocks/CU:
  // two independent barrier domains per CU -> phase overlap (convoy-break)
  attn_fused<<<dim3(448), dim3(256), 0, stream>>>(x, wsm, wst, mask, scale, out);
}

// Round 6
// 210.274 us; speedup vs baseline: 2.4287x; 1.0070x over previous
//
#include <hip/hip_runtime.h>

#define NQ 1764
#define NQP 1792             // keys padded to 28*64, zero-filled by prep
#define DIM 256
#define KT 32                // keys per attn tile
#define NT 56                // all key tiles, every block streams them
#define QBLK 64              // queries per block (28 blocks/batch)

// ---- attn LDS map (halfword units) ----
#define RM_SZ (KT * DIM)                  // 8192 hw: [32 keys][256 d]
#define TR_SZ (DIM * KT)                  // 8192 hw: [256 d][32 keys]
#define BUF_SZ (RM_SZ + TR_SZ)            // 16384
#define P_OFF (2 * BUF_SZ)                // 32768
#define P_STRIDE 40
#define P_SZ (2 * 32 * P_STRIDE)          // 2560 hw: [2 pairs][32 q][40]
#define L_OFF_HW (P_OFF + P_SZ)           // 35328: l-merge region, 128 floats
#define SM_TOTAL (L_OFF_HW + 256)         // 35584 hw = 71168 B -> 2 blocks/CU

// ---- workspace map (ushort units) ----
#define WS_MRM_SZ (16 * NQP * DIM)
#define WS_MTR_SZ (16 * DIM * NQP)

typedef __attribute__((ext_vector_type(4))) short short4v;
typedef __attribute__((ext_vector_type(8))) short short8v;
typedef __attribute__((ext_vector_type(4))) float float4v;

static __device__ __forceinline__ ushort f2bf(float f) {
  union { float f; unsigned u; } v; v.f = f;
  return (ushort)((v.u + 0x7FFFu + ((v.u >> 16) & 1u)) >> 16);  // RNE
}

// async global->LDS DMA, 16 B per lane; LDS dest = wave-uniform base + lane*16
static __device__ __forceinline__ void dma16(const void* g, void* l) {
  __builtin_amdgcn_global_load_lds(
      (__attribute__((address_space(1))) void*)(void*)g,
      (__attribute__((address_space(3))) void*)l, 16, 0, 0);
}

// ============================ prep: m -> bf16 RM + TR ============================
// (round-4 version, verified) smf chunk-XOR swizzled: logical (row,d) at float
// index row*260 + ((d>>2)^(row>>3))*4 + (d&3); transpose gather conflict-free,
// mtr writes 128B-contiguous per 8 lanes.
__global__ __launch_bounds__(256)
void prep_m(const float* __restrict__ mg, ushort* __restrict__ mrm,
            ushort* __restrict__ mtr)
{
  __shared__ float smf[64 * 260];
  const int tid = threadIdx.x;
  const int b   = blockIdx.x & 15;
  const int kt  = blockIdx.x >> 4;      // 0..27, 64-key chunks
  const int k0  = kt * 64;
  const float* mb = mg + (size_t)b * NQ * DIM;

  #pragma unroll
  for (int i = 0; i < 16; ++i) {
    const int idx = i * 256 + tid;
    const int row = idx >> 6;           // 0..63 (key within chunk)
    const int ch  = idx & 63;           // 4-float chunk of d
    const int c4  = ch * 4;
    const int gk  = k0 + row;
    float4v v = (gk < NQ) ? *(const float4v*)(mb + (size_t)gk * DIM + c4)
                          : (float4v){0.f, 0.f, 0.f, 0.f};
    *(float4v*)&smf[row * 260 + ((ch ^ (row >> 3)) << 2)] = v;
    union { short4v v4; short e[4]; } h;
    #pragma unroll
    for (int j = 0; j < 4; ++j) h.e[j] = (short)f2bf(v[j]);
    *(short4v*)(mrm + ((size_t)b * NQP + k0 + row) * DIM + c4) = h.v4;
  }
  __syncthreads();

  const int wv = tid >> 6;        // wave 0..3
  const int ln = tid & 63;
  const int dr = ln >> 3;         // 0..7: d-row within the 8-row strip
  const int kc = ln & 7;          // 0..7: 16B key-chunk within the 64-key block
  #pragma unroll
  for (int it = 0; it < 8; ++it) {
    const int d  = wv * 64 + it * 8 + dr;
    const int dc = d >> 2;        // logical 4-float chunk of d
    const int de = d & 3;
    union { short8v v; short e[8]; } u;
    #pragma unroll
    for (int j = 0; j < 8; ++j)
      u.e[j] = (short)f2bf(smf[(kc * 8 + j) * 260 + ((dc ^ kc) << 2) + de]);
    *(short8v*)(mtr + ((size_t)b * DIM + d) * NQP + k0 + kc * 8) = u.v;
  }
}

// ============================ attention ============================
// LDS-PIPE REBALANCE: 448 blocks x 4 waves, 2 blocks/CU (round-5 convoy-break
// kept). Wave w = (pair p = w>>1, half h = w&1): owns 32 queries (2 subtiles)
// of pair p; computes key-half h of QK and d-half h of PV. Per wave-iter:
// 18 ds_read_b128 feeding 32 MFMAs (was 34/32 at 16 q/wave) -> LDS read
// demand -47% (LDS pipe was ~70% busy: 8 waves x ~460cy / 5250cy iter).
// Two barriers/iter: QK writes P (both halves) -> barrier -> PV reads full-K
// P. Staging issued after barrier2 (overlaps PV; barrier2 drains nothing).
// l is a pure final sum (no max-rescale) -> per-half partials merged once in
// the epilogue via a 128-float LDS region. b = blockIdx&15 preserved -> m
// stays L2-resident per XCD (round-3 lesson: FETCH must stay ~43MB).

static __device__ __forceinline__ void stage_tile(const ushort* mrb, const ushort* mtb,
                                                  ushort* smb, int k0, int w, int lane)
{
  // RM [k][cs] <- global d-chunk cs^(k&7)  (swizzle in the global address)
  #pragma unroll
  for (int j = 0; j < 4; ++j) {
    const int L  = (w * 4 + j) * 64 + lane;   // 0..1023
    const int k  = L >> 5;
    const int cs = L & 31;
    const int gc = cs ^ (k & 7);
    dma16(mrb + (size_t)(k0 + k) * DIM + gc * 8, smb + (w * 4 + j) * 512);
  }
  // TR [d][t] <- global key-chunk t ^ (d&3) ^ ((d>>2)&3)
  #pragma unroll
  for (int j = 0; j < 4; ++j) {
    const int L = (w * 4 + j) * 64 + lane;
    const int d = L >> 2;
    const int t = L & 3;
    const int kc = (t ^ (d & 3) ^ ((d >> 2) & 3)) & 3;
    dma16(mtb + (size_t)d * NQP + k0 + kc * 8, smb + RM_SZ + (w * 4 + j) * 512);
  }
}

__global__ __launch_bounds__(256, 2)
void attn_fused(const float* __restrict__ x, const ushort* __restrict__ mrm,
                const ushort* __restrict__ mtr, const int* __restrict__ maskg,
                const float* __restrict__ scale, float* __restrict__ out)
{
  __shared__ ushort sm[SM_TOTAL];
  const int tid  = threadIdx.x;
  const int w    = tid >> 6;      // 0..3
  const int lane = tid & 63;
  const int l15  = lane & 15;
  const int quad = lane >> 4;
  const int l7   = l15 & 7;
  const int p    = w >> 1;        // query pair: q 32p .. 32p+31
  const int h    = w & 1;         // key half (QK) and d half (PV)

  const int b      = blockIdx.x & 15;
  const int qblk   = blockIdx.x >> 4;     // 0..27
  const int qbase0 = qblk * QBLK;
  const int qbase  = qbase0 + p * 32;

  const float*  xb  = x + (size_t)b * NQ * DIM;
  const ushort* mrb = mrm + (size_t)b * NQP * DIM;
  const ushort* mtb = mtr + (size_t)b * DIM * NQP;
  const int*    mkb = maskg + (size_t)b * NQ;
  float*        ob  = out + (size_t)b * NQ * (2 * DIM);

  // ---- resident Q fragments: two 16-q subtiles, Q = x*scale, bf16, A-layout ----
  short8v qa0[8], qa1[8];
  {
    int q0 = qbase + l15;      q0 = q0 < NQ ? q0 : NQ - 1;
    int q1 = qbase + 16 + l15; q1 = q1 < NQ ? q1 : NQ - 1;
    const float* xr0 = xb + (size_t)q0 * DIM;
    const float* xr1 = xb + (size_t)q1 * DIM;
    #pragma unroll
    for (int kk = 0; kk < 8; ++kk) {
      const int dof = kk * 32 + quad * 8;
      const float4v sa = *(const float4v*)(scale + dof);
      const float4v sb = *(const float4v*)(scale + dof + 4);
      const float4v a0 = *(const float4v*)(xr0 + dof);
      const float4v a1 = *(const float4v*)(xr0 + dof + 4);
      const float4v b0 = *(const float4v*)(xr1 + dof);
      const float4v b1 = *(const float4v*)(xr1 + dof + 4);
      union { short8v v; short e[8]; } u0, u1;
      #pragma unroll
      for (int j = 0; j < 4; ++j) {
        u0.e[j]     = (short)f2bf(a0[j] * sa[j]);
        u0.e[j + 4] = (short)f2bf(a1[j] * sb[j]);
        u1.e[j]     = (short)f2bf(b0[j] * sa[j]);
        u1.e[j + 4] = (short)f2bf(b1[j] * sb[j]);
      }
      qa0[kk] = u0.v;
      qa1[kk] = u1.v;
    }
  }

  float4v o0[8], o1[8];   // dt range h*8 .. h*8+7 for both subtiles
  #pragma unroll
  for (int dt = 0; dt < 8; ++dt) {
    o0[dt] = (float4v){0.f, 0.f, 0.f, 0.f};
    o1[dt] = (float4v){0.f, 0.f, 0.f, 0.f};
  }
  float l0[4] = {0.f, 0.f, 0.f, 0.f};   // key-half-h partial sums
  float l1[4] = {0.f, 0.f, 0.f, 0.f};

  // prologue: stage tile 0 -> buf 0; this wave's half-tile mask
  stage_tile(mrb, mtb, sm, 0, w, lane);
  int mvc = mkb[h * 16 + l15];
  int mvn = 0;

  #pragma unroll 1
  for (int t = 0; t < NT; ++t) {
    __syncthreads();   // barrier1: tile t staged (drains DMA), P[t-1] consumed

    const ushort* rmp = sm + (t & 1) * BUF_SZ;
    const ushort* trp = rmp + RM_SZ;

    // ---- QK, key half h: S = Q·m^T for 16 keys, both q-subtiles ----
    {
      float4v s0A = (float4v){0.f, 0.f, 0.f, 0.f};
      float4v s0B = (float4v){0.f, 0.f, 0.f, 0.f};
      float4v s1A = (float4v){0.f, 0.f, 0.f, 0.f};
      float4v s1B = (float4v){0.f, 0.f, 0.f, 0.f};
      const ushort* rowp = rmp + (h * 16 + l15) * DIM;
      #pragma unroll
      for (int kk = 0; kk < 4; ++kk) {
        const short8v bvA = *(const short8v*)(rowp + (((kk * 4 + quad) ^ l7) * 8));
        const short8v bvB = *(const short8v*)(rowp + ((((kk + 4) * 4 + quad) ^ l7) * 8));
        s0A = __builtin_amdgcn_mfma_f32_16x16x32_bf16(qa0[kk], bvA, s0A, 0, 0, 0);
        s0B = __builtin_amdgcn_mfma_f32_16x16x32_bf16(qa0[kk + 4], bvB, s0B, 0, 0, 0);
        s1A = __builtin_amdgcn_mfma_f32_16x16x32_bf16(qa1[kk], bvA, s1A, 0, 0, 0);
        s1B = __builtin_amdgcn_mfma_f32_16x16x32_bf16(qa1[kk + 4], bvB, s1B, 0, 0, 0);
      }
      // P write: logical key-chunk (h*2 + l15>>3) stored at chunk ^ quad
      // (writer row>>2 & 3 == quad -> involution with the read swizzle)
      const int pwc = (((h * 2 + (l15 >> 3)) ^ quad) << 3) + l7;
      #pragma unroll
      for (int r = 0; r < 4; ++r) {
        const float pv0 = mvc ? exp2f((s0A[r] + s0B[r]) * 1.44269504089f) : 0.0f;
        const float pv1 = mvc ? exp2f((s1A[r] + s1B[r]) * 1.44269504089f) : 0.0f;
        l0[r] += pv0;
        l1[r] += pv1;
        sm[P_OFF + (p * 32 + quad * 4 + r) * P_STRIDE + pwc] = f2bf(pv0);
        sm[P_OFF + (p * 32 + 16 + quad * 4 + r) * P_STRIDE + pwc] = f2bf(pv1);
      }
    }

    __syncthreads();   // barrier2: full-K P ready (no DMA outstanding here)

    // stage t+1 + mask prefetch: overlaps PV, drains at barrier1[t+1]
    if (t + 1 < NT) {
      stage_tile(mrb, mtb, sm + ((t + 1) & 1) * BUF_SZ, (t + 1) * KT, w, lane);
      const int key = (t + 1) * KT + h * 16 + l15;
      mvn = (key < NQ) ? mkb[key] : 0;
    }

    // ---- PV, d half h: O += P·m over all 32 keys ----
    {
      // reader row>>2 & 3 == l15>>2: physical chunk = logical(quad) ^ swz
      const int pswz = ((quad ^ (l15 >> 2)) & 3) << 3;
      const short8v pa0 = *(const short8v*)&sm[P_OFF + (p * 32 + l15) * P_STRIDE + pswz];
      const short8v pa1 = *(const short8v*)&sm[P_OFF + (p * 32 + 16 + l15) * P_STRIDE + pswz];
      #pragma unroll
      for (int dt = 0; dt < 8; ++dt) {
        const int d = (h * 8 + dt) * 16 + l15;
        const short8v bv = *(const short8v*)(
            trp + d * KT + (((quad ^ (d & 3) ^ ((d >> 2) & 3)) & 3) * 8));
        o0[dt] = __builtin_amdgcn_mfma_f32_16x16x32_bf16(pa0, bv, o0[dt], 0, 0, 0);
        o1[dt] = __builtin_amdgcn_mfma_f32_16x16x32_bf16(pa1, bv, o1[dt], 0, 0, 0);
      }
    }
    mvc = mvn;
  }

  // ---- reduce partial l over the 16 lanes of each quad ----
  float la0[4], la1[4];
  #pragma unroll
  for (int r = 0; r < 4; ++r) {
    float a = l0[r], c = l1[r];
    a += __shfl_xor(a, 1); a += __shfl_xor(a, 2);
    a += __shfl_xor(a, 4); a += __shfl_xor(a, 8);
    c += __shfl_xor(c, 1); c += __shfl_xor(c, 2);
    c += __shfl_xor(c, 4); c += __shfl_xor(c, 8);
    la0[r] = a;
    la1[r] = c;
  }

  // ---- merge the two key-half partials: L[p][qs][h][16 q] ----
  float* Lf = (float*)(sm + L_OFF_HW);
  if (l15 == 0) {
    #pragma unroll
    for (int r = 0; r < 4; ++r) {
      Lf[((p * 2 + 0) * 2 + h) * 16 + quad * 4 + r] = la0[r];
      Lf[((p * 2 + 1) * 2 + h) * 16 + quad * 4 + r] = la1[r];
    }
  }
  __syncthreads();
  float il0[4], il1[4];
  #pragma unroll
  for (int r = 0; r < 4; ++r) {
    il0[r] = 1.0f / (Lf[((p * 2 + 0) * 2 + 0) * 16 + quad * 4 + r] +
                     Lf[((p * 2 + 0) * 2 + 1) * 16 + quad * 4 + r]);
    il1[r] = 1.0f / (Lf[((p * 2 + 1) * 2 + 0) * 16 + quad * 4 + r] +
                     Lf[((p * 2 + 1) * 2 + 1) * 16 + quad * 4 + r]);
  }

  // ---- O transpose through LDS (per-pair [32 q][260] fp32; disjoint from L) ----
  float* ew = (float*)sm + p * 8320;
  #pragma unroll
  for (int dt = 0; dt < 8; ++dt) {
    #pragma unroll
    for (int r = 0; r < 4; ++r) {
      ew[(quad * 4 + r) * 260 + (h * 8 + dt) * 16 + l15]      = o0[dt][r] * il0[r];
      ew[(16 + quad * 4 + r) * 260 + (h * 8 + dt) * 16 + l15] = o1[dt][r] * il1[r];
    }
  }
  __syncthreads();

  // ---- coalesced float4 stores: pair's 2 waves cover [32 q][256 d] ----
  #pragma unroll
  for (int i = 0; i < 16; ++i) {
    const int idx = i * 128 + h * 64 + lane;   // 0..2047 within pair
    const int row = idx >> 6;                  // 0..31
    const int c4  = (idx & 63) * 4;
    const int q   = qbase0 + p * 32 + row;
    if (q < NQ) {
      const float4v v = *(const float4v*)&ew[row * 260 + c4];
      *(float4v*)(ob + (size_t)q * (2 * DIM) + DIM + c4) = v;
    }
  }

  // ---- copy x into first half of concat (block's own 64 queries) ----
  #pragma unroll
  for (int i = 0; i < 16; ++i) {
    const int idx = i * 256 + tid;      // 0..4095
    const int row = idx >> 6;           // 0..63
    const int c4  = (idx & 63) * 4;
    const int q   = qbase0 + row;
    if (q < NQ) {
      const float4v v = *(const float4v*)(xb + (size_t)q * DIM + c4);
      *(float4v*)(ob + (size_t)q * (2 * DIM) + c4) = v;
    }
  }
}

extern "C" void kernel_launch(void* const* d_in, const int* in_sizes, int n_in,
                              void* d_out, int out_size, void* d_ws, size_t ws_size,
                              hipStream_t stream) {
  const float* x     = (const float*)d_in[0];
  const float* mem   = (const float*)d_in[1];
  const int*   mask  = (const int*)d_in[2];
  // d_in[3] = w_lin: cancels in softmax (per-row constant) — unused
  const float* scale = (const float*)d_in[4];
  float* out = (float*)d_out;

  ushort* wsm = (ushort*)d_ws;               // bf16 m, row-major [16][1792][256]
  ushort* wst = wsm + WS_MRM_SZ;             // bf16 m, transposed [16][256][1792]

  prep_m<<<dim3(448), dim3(256), 0, stream>>>(mem, wsm, wst);
  // 16 batches x 28 q-blocks of 64 queries = 448 blocks, 2 blocks/CU:
  // independent barrier domains (round-5 convoy-break) + K/d-half wave split
  attn_fused<<<dim3(448), dim3(256), 0, stream>>>(x, wsm, wst, mask, scale, out);
}